// Round 15
// baseline (398.554 us; speedup 1.0000x reference)
//
#include <hip/hip_runtime.h>
#include <math.h>

// ---- problem constants (from reference) ----
constexpr int B_  = 4;
constexpr int S_  = 4096;
constexpr int D_  = 1024;   // DIM
constexpr int IN_ = 2048;   // INNER
constexpr float EPS_ = 1e-8f;
constexpr int NCH_ = 128;         // chunks per sequence for the scan
constexpr int CS_  = S_ / NCH_;   // 32 timesteps per chunk
constexpr float LOG2E_ = 1.4426950408889634f;

typedef __attribute__((ext_vector_type(8))) _Float16 f16x8;
typedef __attribute__((ext_vector_type(2))) _Float16 h2;
typedef __attribute__((ext_vector_type(4))) float    f32x4;

#define BAR() asm volatile("s_barrier" ::: "memory")

// ---- helpers ----
__device__ __forceinline__ h2 pkrtz(float a, float b) {
  auto r = __builtin_amdgcn_cvt_pkrtz(a, b);
  union { decltype(r) r_; h2 h; } c; c.r_ = r; return c.h;
}
__device__ __forceinline__ unsigned packh2(float a, float b) {
  auto r = __builtin_amdgcn_cvt_pkrtz(a, b);
  union { decltype(r) r_; unsigned u; } c; c.r_ = r; return c.u;
}
__device__ __forceinline__ void unpack_h8(uint4 v, float* f) {
  union { uint4 u; _Float16 h[8]; } c; c.u = v;
  #pragma unroll
  for (int i = 0; i < 8; ++i) f[i] = (float)c.h[i];
}
__device__ __forceinline__ float siluf(float x) {
  return x * __builtin_amdgcn_rcpf(1.0f + __builtin_amdgcn_exp2f(-x * LOG2E_));
}

// async global->LDS, 16 B per lane (wave-uniform LDS base + lane*16)
__device__ __forceinline__ void gload16(const void* g, void* l) {
  __builtin_amdgcn_global_load_lds(
      (const __attribute__((address_space(1))) void*)g,
      (__attribute__((address_space(3))) void*)l,
      16, 0, 0);
}

// ---------------------------------------------------------------------------
// fp32 -> f16 conversion for two buffers in one launch (8 elems/thread)
// ---------------------------------------------------------------------------
__launch_bounds__(256)
__global__ void cvt_f16_2(const float* __restrict__ in0, unsigned* __restrict__ out0,
                          long n8_0,
                          const float* __restrict__ in1, unsigned* __restrict__ out1,
                          long n8_1)
{
  const long total  = n8_0 + n8_1;
  const long stride = (long)gridDim.x * blockDim.x;
  for (long t = (long)blockIdx.x * blockDim.x + threadIdx.x; t < total; t += stride) {
    const float* in  = (t < n8_0) ? in0  : in1;
    unsigned*    out = (t < n8_0) ? out0 : out1;
    const long   i   = (t < n8_0) ? t    : t - n8_0;
    const float4 a = *(const float4*)(in + i * 8);
    const float4 b = *(const float4*)(in + i * 8 + 4);
    uint4 o;
    o.x = packh2(a.x, a.y);
    o.y = packh2(a.z, a.w);
    o.z = packh2(b.x, b.y);
    o.w = packh2(b.z, b.w);
    *(uint4*)(out + i * 4) = o;
  }
}

__launch_bounds__(256)
__global__ void cvt_f16(const float* __restrict__ in, unsigned* __restrict__ outp,
                        long n8)
{
  const long stride = (long)gridDim.x * blockDim.x;
  for (long i = (long)blockIdx.x * blockDim.x + threadIdx.x; i < n8; i += stride) {
    const float4 a = *(const float4*)(in + i * 8);
    const float4 b = *(const float4*)(in + i * 8 + 4);
    uint4 o;
    o.x = packh2(a.x, a.y);
    o.y = packh2(a.z, a.w);
    o.z = packh2(b.x, b.y);
    o.w = packh2(b.z, b.w);
    *(uint4*)(outp + i * 4) = o;
  }
}

// ---------------------------------------------------------------------------
// f16 MFMA NT GEMM, 4-phase schedule, 256x256 tile, BK=64, 8 waves (2Mx4N),
// double-buffered LDS (128 KiB), XOR-16B-block swizzle, counted vmcnt(8),
// setprio, bijective XCD swizzle, staging spread 2-2-4 across phases 1/2/3.
// (r10 configuration — frozen; 840 TF plateau verified across 4 variants)
// MODE 0: split epilogue -> xmin(f16) | silu(z)(f16) via per-wave LDS
//         transpose (16B full-line stores).
// MODE 1: fp32 out, direct stores (64B-contiguous per 16 lanes).
// ---------------------------------------------------------------------------
template<int MODE>
__launch_bounds__(512, 2)
__global__ void gemm_mfma(const unsigned short* __restrict__ Ab,
                          const unsigned short* __restrict__ Bb,
                          const float* __restrict__ bias,
                          void* __restrict__ out0,
                          unsigned short* __restrict__ out1,
                          int M, int N, int K)
{
  constexpr int BM = 256, BN = 256, BK = 64;
  __shared__ __align__(16) unsigned short As[2][BM * BK];  // 2 x 32 KB
  __shared__ __align__(16) unsigned short Bs[2][BN * BK];  // 2 x 32 KB

  const int tid  = threadIdx.x;
  const int lane = tid & 63;
  const int w    = tid >> 6;       // 0..7
  const int wm   = w >> 2;         // 0..1  (M half)
  const int wn   = w & 3;          // 0..3  (N quarter)

  // bijective XCD swizzle
  const int GX  = gridDim.x;
  const int nwg = GX * gridDim.y;           // divisible by 8 for our shapes
  int lin = blockIdx.y * GX + blockIdx.x;
  lin = (lin & 7) * (nwg >> 3) + (lin >> 3);
  const int m0 = (lin / GX) * BM;
  const int n0 = (lin % GX) * BN;
  const int NT = K / BK;

  // staging geometry
  const int sr   = lane >> 3;                   // 0..7 row-in-slice
  const int sblk = ((lane & 7) ^ sr) * 8;       // pre-swizzled global col

  // fragment read geometry
  const int fr  = lane & 15;
  const int fb0 = (((lane >> 4) + 0) ^ (lane & 7)) * 8;
  const int fb1 = (((lane >> 4) + 4) ^ (lane & 7)) * 8;

  auto stage64 = [&](const unsigned short* Gp, int Kd, int grow0, int kOff,
                     unsigned short* lchunk) {
    gload16(Gp + (size_t)(grow0 + w * 8 + sr) * Kd + kOff + sblk,
            lchunk + (w * 8) * BK);
  };

  f32x4 acc[8][4] = {};

  // ---- prologue: stage tiles 0 and 1 ----
  #pragma unroll
  for (int c = 0; c < 4; ++c) stage64(Ab, K, m0 + c * 64, 0, &As[0][c * 64 * BK]);
  #pragma unroll
  for (int c = 0; c < 4; ++c) stage64(Bb, K, n0 + c * 64, 0, &Bs[0][c * 64 * BK]);
  #pragma unroll
  for (int c = 0; c < 4; ++c) stage64(Ab, K, m0 + c * 64, BK, &As[1][c * 64 * BK]);
  #pragma unroll
  for (int c = 0; c < 4; ++c) stage64(Bb, K, n0 + c * 64, BK, &Bs[1][c * 64 * BK]);
  asm volatile("s_waitcnt vmcnt(8)" ::: "memory");   // tile 0 landed
  BAR();

  for (int t = 0; t < NT; ++t) {
    const int cur = t & 1;
    const unsigned short* AL = As[cur];
    const unsigned short* BL = Bs[cur];
    const int  nxtK = (t + 2) * BK;
    const bool more = (t + 2 < NT);

    f16x8 af[4][2], bf[4][2];

    // ---- phase 0: quadrant (mq=0, nq=0) — 12 ds_reads, 16 MFMA
    #pragma unroll
    for (int i = 0; i < 4; ++i) {
      const int row = wm * 128 + i * 16 + fr;
      af[i][0] = *(const f16x8*)&AL[row * BK + fb0];
      af[i][1] = *(const f16x8*)&AL[row * BK + fb1];
    }
    #pragma unroll
    for (int j = 0; j < 2; ++j) {
      const int row = wn * 64 + j * 16 + fr;
      bf[j][0] = *(const f16x8*)&BL[row * BK + fb0];
      bf[j][1] = *(const f16x8*)&BL[row * BK + fb1];
    }
    BAR();
    __builtin_amdgcn_s_setprio(1);
    #pragma unroll
    for (int i = 0; i < 4; ++i)
      #pragma unroll
      for (int j = 0; j < 2; ++j) {
        acc[i][j] = __builtin_amdgcn_mfma_f32_16x16x32_f16(af[i][0], bf[j][0], acc[i][j], 0, 0, 0);
        acc[i][j] = __builtin_amdgcn_mfma_f32_16x16x32_f16(af[i][1], bf[j][1], acc[i][j], 0, 0, 0);
      }
    __builtin_amdgcn_s_setprio(0);
    BAR();

    // ---- phase 1: (mq=0, nq=1) — 4 ds_reads; stage A chunks 0,2 of t+2
    #pragma unroll
    for (int j = 2; j < 4; ++j) {
      const int row = wn * 64 + j * 16 + fr;
      bf[j][0] = *(const f16x8*)&BL[row * BK + fb0];
      bf[j][1] = *(const f16x8*)&BL[row * BK + fb1];
    }
    if (more) {
      stage64(Ab, K, m0 +   0, nxtK, &As[cur][0]);
      stage64(Ab, K, m0 + 128, nxtK, &As[cur][128 * BK]);
    }
    BAR();
    __builtin_amdgcn_s_setprio(1);
    #pragma unroll
    for (int i = 0; i < 4; ++i)
      #pragma unroll
      for (int j = 2; j < 4; ++j) {
        acc[i][j] = __builtin_amdgcn_mfma_f32_16x16x32_f16(af[i][0], bf[j][0], acc[i][j], 0, 0, 0);
        acc[i][j] = __builtin_amdgcn_mfma_f32_16x16x32_f16(af[i][1], bf[j][1], acc[i][j], 0, 0, 0);
      }
    __builtin_amdgcn_s_setprio(0);
    BAR();

    // ---- phase 2: (mq=1, nq=0) — 8 ds_reads; stage B chunks 0,1 of t+2
    #pragma unroll
    for (int i = 0; i < 4; ++i) {
      const int row = wm * 128 + 64 + i * 16 + fr;
      af[i][0] = *(const f16x8*)&AL[row * BK + fb0];
      af[i][1] = *(const f16x8*)&AL[row * BK + fb1];
    }
    if (more) {
      stage64(Bb, K, n0 +   0, nxtK, &Bs[cur][0]);
      stage64(Bb, K, n0 +  64, nxtK, &Bs[cur][64 * BK]);
    }
    BAR();
    __builtin_amdgcn_s_setprio(1);
    #pragma unroll
    for (int i = 0; i < 4; ++i)
      #pragma unroll
      for (int j = 0; j < 2; ++j) {
        acc[4 + i][j] = __builtin_amdgcn_mfma_f32_16x16x32_f16(af[i][0], bf[j][0], acc[4 + i][j], 0, 0, 0);
        acc[4 + i][j] = __builtin_amdgcn_mfma_f32_16x16x32_f16(af[i][1], bf[j][1], acc[4 + i][j], 0, 0, 0);
      }
    __builtin_amdgcn_s_setprio(0);
    BAR();

    // ---- phase 3: (mq=1, nq=1) — 0 ds_reads; stage A chunks 1,3 + B chunks 2,3
    if (more) {
      stage64(Ab, K, m0 +  64, nxtK, &As[cur][64 * BK]);
      stage64(Ab, K, m0 + 192, nxtK, &As[cur][192 * BK]);
      stage64(Bb, K, n0 + 128, nxtK, &Bs[cur][128 * BK]);
      stage64(Bb, K, n0 + 192, nxtK, &Bs[cur][192 * BK]);
    }
    BAR();
    __builtin_amdgcn_s_setprio(1);
    #pragma unroll
    for (int i = 0; i < 4; ++i)
      #pragma unroll
      for (int j = 2; j < 4; ++j) {
        acc[4 + i][j] = __builtin_amdgcn_mfma_f32_16x16x32_f16(af[i][0], bf[j][0], acc[4 + i][j], 0, 0, 0);
        acc[4 + i][j] = __builtin_amdgcn_mfma_f32_16x16x32_f16(af[i][1], bf[j][1], acc[4 + i][j], 0, 0, 0);
      }
    __builtin_amdgcn_s_setprio(0);
    if (more) asm volatile("s_waitcnt vmcnt(8)" ::: "memory");
    else      asm volatile("s_waitcnt vmcnt(0)" ::: "memory");
    BAR();
  }

  // ---- epilogue ----
  const int col = lane & 15;
  const int rb4 = (lane >> 4) * 4;

  if (MODE == 1) {
    #pragma unroll
    for (int j = 0; j < 4; ++j) {
      const int n  = n0 + wn * 64 + j * 16 + col;
      const float bv = bias[n];
      #pragma unroll
      for (int i = 0; i < 8; ++i) {
        const int mb = m0 + wm * 128 + i * 16 + rb4;
        #pragma unroll
        for (int r = 0; r < 4; ++r)
          ((float*)out0)[(size_t)(mb + r) * N + n] = acc[i][j][r] + bv;
      }
    }
  } else {
    // f16 split outputs via per-wave LDS transpose -> 16B full-line stores.
    constexpr int RS = 72;
    unsigned short* eb = (w < 4) ? ((unsigned short*)As + w * (64 * RS))
                                 : ((unsigned short*)Bs + (w - 4) * (64 * RS));
    const bool zhalf = (n0 >= IN_);   // block-uniform
    float bv[4];
    #pragma unroll
    for (int j = 0; j < 4; ++j) bv[j] = bias[n0 + wn * 64 + j * 16 + col];

    const int lrow = lane >> 3;
    const int lc8  = (lane & 7) * 8;
    unsigned short* dst = zhalf ? out1 : (unsigned short*)out0;
    const int ncol0 = (zhalf ? n0 - IN_ : n0) + wn * 64 + lc8;

    #pragma unroll
    for (int h = 0; h < 2; ++h) {
      asm volatile("s_waitcnt lgkmcnt(0)" ::: "memory");
      #pragma unroll
      for (int i2 = 0; i2 < 4; ++i2)
        #pragma unroll
        for (int j = 0; j < 4; ++j)
          #pragma unroll
          for (int r = 0; r < 4; ++r) {
            const float v = acc[h * 4 + i2][j][r] + bv[j];
            ((_Float16*)eb)[(i2 * 16 + rb4 + r) * RS + j * 16 + col] = (_Float16)v;
          }
      asm volatile("s_waitcnt lgkmcnt(0)" ::: "memory");
      #pragma unroll
      for (int it = 0; it < 8; ++it) {
        const int row = it * 8 + lrow;
        uint4 d = *(const uint4*)&eb[row * RS + lc8];
        if (zhalf) {
          float f[8];
          unpack_h8(d, f);
          d.x = packh2(siluf(f[0]), siluf(f[1]));
          d.y = packh2(siluf(f[2]), siluf(f[3]));
          d.z = packh2(siluf(f[4]), siluf(f[5]));
          d.w = packh2(siluf(f[6]), siluf(f[7]));
        }
        const int m = m0 + wm * 128 + h * 64 + row;
        *(uint4*)(dst + (size_t)m * IN_ + ncol0) = d;
      }
    }
  }
}

// ---------------------------------------------------------------------------
// causal depthwise conv (K=4, left pad 3) + SiLU.  f16 in/out.
// 8 channels x 4 timesteps per thread: 7 row-loads for 4 outputs.
// ---------------------------------------------------------------------------
__launch_bounds__(256)
__global__ void conv_silu_k(const uint4* __restrict__ xm,
                            const float* __restrict__ cw,   // (IN_,1,4)
                            const float* __restrict__ cb,
                            uint4* __restrict__ act)
{
  const int t = blockIdx.x * 256 + threadIdx.x;   // grid sized exactly
  const int c8 = t & 255;                         // channel group (IN_/8)
  const int s4 = (t >> 8) & (S_ / 4 - 1);         // timestep group
  const int b  = t >> 18;
  const int c  = c8 * 8;
  constexpr int RW = IN_ / 8;                     // row stride in uint4

  float w[8][4];
  #pragma unroll
  for (int j = 0; j < 8; ++j)
    *(float4*)w[j] = *(const float4*)(cw + (size_t)(c + j) * 4);
  float bias8[8];
  *(float4*)(bias8)     = *(const float4*)(cb + c);
  *(float4*)(bias8 + 4) = *(const float4*)(cb + c + 4);

  const size_t rowb = ((size_t)b * S_ + s4 * 4) * RW + c8;
  float xf[7][8];
  #pragma unroll
  for (int i = 0; i < 7; ++i) {
    if (s4 == 0 && i < 3) {
      #pragma unroll
      for (int j = 0; j < 8; ++j) xf[i][j] = 0.0f;
    } else {
      unpack_h8(xm[rowb + (long)(i - 3) * RW], xf[i]);
    }
  }

  #pragma unroll
  for (int o = 0; o < 4; ++o) {
    float r[8];
    #pragma unroll
    for (int j = 0; j < 8; ++j) r[j] = bias8[j];
    #pragma unroll
    for (int k = 0; k < 4; ++k)
      #pragma unroll
      for (int j = 0; j < 8; ++j)
        r[j] = fmaf(xf[o + k][j], w[j][k], r[j]);
    uint4 ov;
    ov.x = packh2(siluf(r[0]), siluf(r[1]));
    ov.y = packh2(siluf(r[2]), siluf(r[3]));
    ov.z = packh2(siluf(r[4]), siluf(r[5]));
    ov.w = packh2(siluf(r[6]), siluf(r[7]));
    act[rowb + (size_t)o * RW] = ov;
  }
}

// ---------------------------------------------------------------------------
// grouped 16x16 gate projections + per-chunk scan partials — LINEAR domain,
// TWO output channels per thread (o = 2*o2, 2*o2+1): shared act loads,
// two independent gate chains for 2x ILP; 8192 waves = one full occupancy
// round at 8 waves/SIMD.
// ---------------------------------------------------------------------------
__launch_bounds__(256)
__global__ void gates_scan(const unsigned* __restrict__ actb,
                           const float* __restrict__ wf,
                           const float* __restrict__ wi,
                           const float* __restrict__ wh,
                           float2* __restrict__ part)   // [B_*IN_][NCH_]
{
  const int T  = blockIdx.x * 256 + threadIdx.x;
  const int o2 = T & 7;                 // output pair index
  const int g  = (T >> 3) & 127;
  const int ck = (T >> 10) & (NCH_ - 1);
  const int b  = T >> 17;

  h2 Wf2[2][8], Wi2[2][8], Wh2[2][8];
  #pragma unroll
  for (int u = 0; u < 2; ++u) {
    const int o = o2 * 2 + u;
    const float* pf = wf + ((size_t)g * 16 + o) * 16;
    const float* pi = wi + ((size_t)g * 16 + o) * 16;
    const float* ph = wh + ((size_t)g * 16 + o) * 16;
    #pragma unroll
    for (int i = 0; i < 8; ++i) {
      Wf2[u][i] = pkrtz(pf[2 * i] * LOG2E_, pf[2 * i + 1] * LOG2E_);  // base-2
      Wi2[u][i] = pkrtz(pi[2 * i] * LOG2E_, pi[2 * i + 1] * LOG2E_);
      Wh2[u][i] = pkrtz(ph[2 * i], ph[2 * i + 1]);
    }
  }

  float q0 = 0.0f, Ss0 = 0.0f;
  float q1 = 0.0f, Ss1 = 0.0f;
  // start at the LAST step of the chunk, walk backward in time
  const unsigned* ap = actb + ((size_t)b * S_ + (size_t)ck * CS_ + (CS_ - 1)) * (IN_ / 2) + g * 8;
  for (int blk = 0; blk < 4; ++blk) {
    float R0 = 1.0f, T0 = 0.0f;
    float R1 = 1.0f, T1 = 0.0f;
    #pragma unroll
    for (int s = 0; s < 8; ++s) {
      union { uint4 u; h2 h[4]; } A0, A1;
      A0.u = *(const uint4*)(ap);
      A1.u = *(const uint4*)(ap + 4);
      ap -= IN_ / 2;
      float fg0 = 0.0f, ig0 = 0.0f, hd0 = 0.0f;
      float fg1 = 0.0f, ig1 = 0.0f, hd1 = 0.0f;
      #pragma unroll
      for (int i = 0; i < 4; ++i) {
        fg0 = __builtin_amdgcn_fdot2(A0.h[i], Wf2[0][i], fg0, false);
        fg1 = __builtin_amdgcn_fdot2(A0.h[i], Wf2[1][i], fg1, false);
        ig0 = __builtin_amdgcn_fdot2(A0.h[i], Wi2[0][i], ig0, false);
        ig1 = __builtin_amdgcn_fdot2(A0.h[i], Wi2[1][i], ig1, false);
        hd0 = __builtin_amdgcn_fdot2(A0.h[i], Wh2[0][i], hd0, false);
        hd1 = __builtin_amdgcn_fdot2(A0.h[i], Wh2[1][i], hd1, false);
      }
      #pragma unroll
      for (int i = 0; i < 4; ++i) {
        fg0 = __builtin_amdgcn_fdot2(A1.h[i], Wf2[0][i + 4], fg0, false);
        fg1 = __builtin_amdgcn_fdot2(A1.h[i], Wf2[1][i + 4], fg1, false);
        ig0 = __builtin_amdgcn_fdot2(A1.h[i], Wi2[0][i + 4], ig0, false);
        ig1 = __builtin_amdgcn_fdot2(A1.h[i], Wi2[1][i + 4], ig1, false);
        hd0 = __builtin_amdgcn_fdot2(A1.h[i], Wh2[0][i + 4], hd0, false);
        hd1 = __builtin_amdgcn_fdot2(A1.h[i], Wh2[1][i + 4], hd1, false);
      }
      // chain 0
      {
        const float Ef = __builtin_amdgcn_exp2f(-fg0);
        const float Ei = __builtin_amdgcn_exp2f(-ig0);
        const float rden = __builtin_amdgcn_rcpf(2.0f + Ef + Ei);
        const float f = (1.0f + Ei) * rden;
        const float i = (1.0f + Ef) * rden;
        const float Eh = __builtin_amdgcn_exp2f(-hd0 * LOG2E_);
        const float gneg = __builtin_amdgcn_rcpf(1.0f + Eh);
        const float gt = (hd0 >= 0.0f) ? (hd0 + 0.5f + EPS_) : gneg;
        T0 = fmaf(i * gt, R0, T0);
        R0 *= f;
      }
      // chain 1
      {
        const float Ef = __builtin_amdgcn_exp2f(-fg1);
        const float Ei = __builtin_amdgcn_exp2f(-ig1);
        const float rden = __builtin_amdgcn_rcpf(2.0f + Ef + Ei);
        const float f = (1.0f + Ei) * rden;
        const float i = (1.0f + Ef) * rden;
        const float Eh = __builtin_amdgcn_exp2f(-hd1 * LOG2E_);
        const float gneg = __builtin_amdgcn_rcpf(1.0f + Eh);
        const float gt = (hd1 >= 0.0f) ? (hd1 + 0.5f + EPS_) : gneg;
        T1 = fmaf(i * gt, R1, T1);
        R1 *= f;
      }
    }
    Ss0 = fmaf(__builtin_amdgcn_exp2f(q0), T0, Ss0);
    q0 += __builtin_amdgcn_logf(R0);   // v_log_f32 = log2
    Ss1 = fmaf(__builtin_amdgcn_exp2f(q1), T1, Ss1);
    q1 += __builtin_amdgcn_logf(R1);
  }
  const size_t base = ((size_t)(b * IN_ + g * 16 + o2 * 2)) * NCH_ + ck;
  part[base]        = make_float2(q0, -q0 + __builtin_amdgcn_logf(Ss0 + 1e-44f));
  part[base + NCH_] = make_float2(q1, -q1 + __builtin_amdgcn_logf(Ss1 + 1e-44f));
}

// ---------------------------------------------------------------------------
// combine chunk partials -> h_last[b, c]   (base-2 domain throughout)
// ---------------------------------------------------------------------------
__launch_bounds__(256)
__global__ void combine_k(const float2* __restrict__ part, float* __restrict__ hlast)
{
  const int seq = blockIdx.x * 256 + threadIdx.x;
  if (seq >= B_ * IN_) return;
  const float2* pp = part + (size_t)seq * NCH_;
  float P = 0.0f, Mx = -INFINITY, Ss = 0.0f;
  for (int c = 0; c < NCH_; ++c) {
    const float2 al = pp[c];
    const float v = al.y - P;
    const float m = fmaxf(Mx, v);
    Ss = Ss * __builtin_amdgcn_exp2f(Mx - m) + __builtin_amdgcn_exp2f(v - m);
    Mx = m;
    P += al.x;
  }
  hlast[seq] = __builtin_amdgcn_exp2f(P + Mx) * Ss;
}

// ---------------------------------------------------------------------------
// G = (h_last + skip*act) * silu(z), written in place over the z buffer.
// ---------------------------------------------------------------------------
__launch_bounds__(256)
__global__ void gfuse_k(const unsigned* __restrict__ actb,
                        unsigned* __restrict__ zb,
                        const float* __restrict__ hlast,
                        const float* __restrict__ skipv)
{
  const size_t total  = (size_t)B_ * S_ * IN_ / 8;
  const size_t stride = (size_t)gridDim.x * blockDim.x;
  for (size_t t = (size_t)blockIdx.x * blockDim.x + threadIdx.x; t < total; t += stride) {
    const size_t e = t * 8;
    const int    c = (int)(e % IN_);
    const int    b = (int)(e / ((size_t)S_ * IN_));
    float a[8], z[8], hl[8], sk[8];
    unpack_h8(*(const uint4*)(actb + e / 2), a);
    unpack_h8(*(const uint4*)(zb   + e / 2), z);
    *(float4*)(hl)     = *(const float4*)(hlast + (size_t)b * IN_ + c);
    *(float4*)(hl + 4) = *(const float4*)(hlast + (size_t)b * IN_ + c + 4);
    *(float4*)(sk)     = *(const float4*)(skipv + c);
    *(float4*)(sk + 4) = *(const float4*)(skipv + c + 4);
    float g[8];
    #pragma unroll
    for (int j = 0; j < 8; ++j) g[j] = (hl[j] + sk[j] * a[j]) * z[j];
    uint4 o;
    o.x = packh2(g[0], g[1]);
    o.y = packh2(g[2], g[3]);
    o.z = packh2(g[4], g[5]);
    o.w = packh2(g[6], g[7]);
    *(uint4*)(zb + e / 2) = o;
  }
}

// ---------------------------------------------------------------------------
extern "C" void kernel_launch(void* const* d_in, const int* in_sizes, int n_in,
                              void* d_out, int out_size, void* d_ws, size_t ws_size,
                              hipStream_t stream)
{
  const float* x     = (const float*)d_in[0];
  const float* w_up  = (const float*)d_in[1];
  const float* b_up  = (const float*)d_in[2];
  const float* cw    = (const float*)d_in[3];
  const float* cb    = (const float*)d_in[4];
  const float* skipv = (const float*)d_in[5];
  const float* w_f   = (const float*)d_in[6];
  const float* w_i   = (const float*)d_in[7];
  const float* w_h   = (const float*)d_in[8];
  const float* w_dn  = (const float*)d_in[9];
  const float* b_dn  = (const float*)d_in[10];
  float* out = (float*)d_out;

  // workspace layout with lifetime-based aliasing (max ~210 MB)
  char* ws = (char*)d_ws;
  unsigned short* xminb = (unsigned short*)(ws);
  unsigned short* wdb   = (unsigned short*)(ws);                    // after conv
  float2*         part  = (float2*)(ws + 8388608ULL);               // after conv
  float*          hlast = (float*)(ws + 16777216ULL);               // after conv
  unsigned short* zb    = (unsigned short*)(ws + 67108864ULL);
  unsigned short* actb  = (unsigned short*)(ws + 134217728ULL);
  unsigned short* xb    = (unsigned short*)(ws + 134217728ULL);     // pre-conv alias
  unsigned short* wub   = (unsigned short*)(ws + 201326592ULL);

  const int M = B_ * S_;   // 16384

  // 0) fp32 -> f16 conversions for MFMA operands (single launch)
  cvt_f16_2<<<2560, 256, 0, stream>>>(
      x,    (unsigned*)xb,  (long)M * D_ / 8,
      w_up, (unsigned*)wub, (long)2 * IN_ * D_ / 8);

  // 1) proj-up: xb @ wub^T + b_up -> xmin(f16) | silu(z)(f16)
  gemm_mfma<0><<<dim3((2 * IN_) / 256, M / 256), 512, 0, stream>>>(
      xb, wub, b_up, xminb, (unsigned short*)zb, M, 2 * IN_, D_);

  // 2) causal depthwise conv + SiLU -> act(f16)  (4 steps x 8 ch / thread)
  conv_silu_k<<<(B_ * (S_ / 4) * (IN_ / 8)) / 256, 256, 0, stream>>>(
      (const uint4*)xminb, cw, cb, (uint4*)actb);

  // 2b) w_down -> f16 (into region freed by xminb)
  cvt_f16<<<256, 256, 0, stream>>>(w_dn, (unsigned*)wdb, (long)D_ * IN_ / 8);

  // 3) grouped gate projections + chunked scan partials (linear, 2 out/thread)
  gates_scan<<<(B_ * 128 * 8 * NCH_) / 256, 256, 0, stream>>>(
      (const unsigned*)actb, w_f, w_i, w_h, part);

  // 4) combine partials -> h_last
  combine_k<<<(B_ * IN_ + 255) / 256, 256, 0, stream>>>(part, hlast);

  // 5) G = (h_last + skip*act) * silu(z), in place over zb
  gfuse_k<<<2048, 256, 0, stream>>>((const unsigned*)actb, (unsigned*)zb, hlast, skipv);

  // 6) proj-down: G(f16) @ wdb^T + b_dn -> out (fp32)
  gemm_mfma<1><<<dim3(D_ / 256, M / 256), 512, 0, stream>>>(
      zb, wdb, b_dn, out, nullptr, M, D_, IN_);
}

// Round 16
// 376.575 us; speedup vs baseline: 1.0584x; 1.0584x over previous
//
#include <hip/hip_runtime.h>
#include <math.h>

// ---- problem constants (from reference) ----
constexpr int B_  = 4;
constexpr int S_  = 4096;
constexpr int D_  = 1024;   // DIM
constexpr int IN_ = 2048;   // INNER
constexpr float EPS_ = 1e-8f;
constexpr int NCH_ = 128;         // chunks per sequence for the scan
constexpr int CS_  = S_ / NCH_;   // 32 timesteps per chunk
constexpr float LOG2E_ = 1.4426950408889634f;

typedef __attribute__((ext_vector_type(8))) _Float16 f16x8;
typedef __attribute__((ext_vector_type(2))) _Float16 h2;
typedef __attribute__((ext_vector_type(4))) float    f32x4;

#define BAR() asm volatile("s_barrier" ::: "memory")

// ---- helpers ----
__device__ __forceinline__ h2 pkrtz(float a, float b) {
  auto r = __builtin_amdgcn_cvt_pkrtz(a, b);
  union { decltype(r) r_; h2 h; } c; c.r_ = r; return c.h;
}
__device__ __forceinline__ unsigned packh2(float a, float b) {
  auto r = __builtin_amdgcn_cvt_pkrtz(a, b);
  union { decltype(r) r_; unsigned u; } c; c.r_ = r; return c.u;
}
__device__ __forceinline__ void unpack_h8(uint4 v, float* f) {
  union { uint4 u; _Float16 h[8]; } c; c.u = v;
  #pragma unroll
  for (int i = 0; i < 8; ++i) f[i] = (float)c.h[i];
}
__device__ __forceinline__ float siluf(float x) {
  return x * __builtin_amdgcn_rcpf(1.0f + __builtin_amdgcn_exp2f(-x * LOG2E_));
}

// async global->LDS, 16 B per lane (wave-uniform LDS base + lane*16)
__device__ __forceinline__ void gload16(const void* g, void* l) {
  __builtin_amdgcn_global_load_lds(
      (const __attribute__((address_space(1))) void*)g,
      (__attribute__((address_space(3))) void*)l,
      16, 0, 0);
}

// ---------------------------------------------------------------------------
// fp32 -> f16 conversion for two buffers in one launch (8 elems/thread)
// ---------------------------------------------------------------------------
__launch_bounds__(256)
__global__ void cvt_f16_2(const float* __restrict__ in0, unsigned* __restrict__ out0,
                          long n8_0,
                          const float* __restrict__ in1, unsigned* __restrict__ out1,
                          long n8_1)
{
  const long total  = n8_0 + n8_1;
  const long stride = (long)gridDim.x * blockDim.x;
  for (long t = (long)blockIdx.x * blockDim.x + threadIdx.x; t < total; t += stride) {
    const float* in  = (t < n8_0) ? in0  : in1;
    unsigned*    out = (t < n8_0) ? out0 : out1;
    const long   i   = (t < n8_0) ? t    : t - n8_0;
    const float4 a = *(const float4*)(in + i * 8);
    const float4 b = *(const float4*)(in + i * 8 + 4);
    uint4 o;
    o.x = packh2(a.x, a.y);
    o.y = packh2(a.z, a.w);
    o.z = packh2(b.x, b.y);
    o.w = packh2(b.z, b.w);
    *(uint4*)(out + i * 4) = o;
  }
}

__launch_bounds__(256)
__global__ void cvt_f16(const float* __restrict__ in, unsigned* __restrict__ outp,
                        long n8)
{
  const long stride = (long)gridDim.x * blockDim.x;
  for (long i = (long)blockIdx.x * blockDim.x + threadIdx.x; i < n8; i += stride) {
    const float4 a = *(const float4*)(in + i * 8);
    const float4 b = *(const float4*)(in + i * 8 + 4);
    uint4 o;
    o.x = packh2(a.x, a.y);
    o.y = packh2(a.z, a.w);
    o.z = packh2(b.x, b.y);
    o.w = packh2(b.z, b.w);
    *(uint4*)(outp + i * 4) = o;
  }
}

// ---------------------------------------------------------------------------
// f16 MFMA NT GEMM, 4-phase schedule, 256x256 tile, BK=64, 8 waves (2Mx4N),
// double-buffered LDS (128 KiB), XOR-16B-block swizzle, counted vmcnt(8),
// setprio, bijective XCD swizzle, staging spread 2-2-4 across phases 1/2/3.
// (r10 configuration — frozen; 840 TF plateau verified across 4 variants)
// MODE 0: split epilogue -> xmin(f16) | silu(z)(f16) via per-wave LDS
//         transpose (16B full-line stores).
// MODE 1: fp32 out, direct stores (64B-contiguous per 16 lanes).
// ---------------------------------------------------------------------------
template<int MODE>
__launch_bounds__(512, 2)
__global__ void gemm_mfma(const unsigned short* __restrict__ Ab,
                          const unsigned short* __restrict__ Bb,
                          const float* __restrict__ bias,
                          void* __restrict__ out0,
                          unsigned short* __restrict__ out1,
                          int M, int N, int K)
{
  constexpr int BM = 256, BN = 256, BK = 64;
  __shared__ __align__(16) unsigned short As[2][BM * BK];  // 2 x 32 KB
  __shared__ __align__(16) unsigned short Bs[2][BN * BK];  // 2 x 32 KB

  const int tid  = threadIdx.x;
  const int lane = tid & 63;
  const int w    = tid >> 6;       // 0..7
  const int wm   = w >> 2;         // 0..1  (M half)
  const int wn   = w & 3;          // 0..3  (N quarter)

  // bijective XCD swizzle
  const int GX  = gridDim.x;
  const int nwg = GX * gridDim.y;           // divisible by 8 for our shapes
  int lin = blockIdx.y * GX + blockIdx.x;
  lin = (lin & 7) * (nwg >> 3) + (lin >> 3);
  const int m0 = (lin / GX) * BM;
  const int n0 = (lin % GX) * BN;
  const int NT = K / BK;

  // staging geometry
  const int sr   = lane >> 3;                   // 0..7 row-in-slice
  const int sblk = ((lane & 7) ^ sr) * 8;       // pre-swizzled global col

  // fragment read geometry
  const int fr  = lane & 15;
  const int fb0 = (((lane >> 4) + 0) ^ (lane & 7)) * 8;
  const int fb1 = (((lane >> 4) + 4) ^ (lane & 7)) * 8;

  auto stage64 = [&](const unsigned short* Gp, int Kd, int grow0, int kOff,
                     unsigned short* lchunk) {
    gload16(Gp + (size_t)(grow0 + w * 8 + sr) * Kd + kOff + sblk,
            lchunk + (w * 8) * BK);
  };

  f32x4 acc[8][4] = {};

  // ---- prologue: stage tiles 0 and 1 ----
  #pragma unroll
  for (int c = 0; c < 4; ++c) stage64(Ab, K, m0 + c * 64, 0, &As[0][c * 64 * BK]);
  #pragma unroll
  for (int c = 0; c < 4; ++c) stage64(Bb, K, n0 + c * 64, 0, &Bs[0][c * 64 * BK]);
  #pragma unroll
  for (int c = 0; c < 4; ++c) stage64(Ab, K, m0 + c * 64, BK, &As[1][c * 64 * BK]);
  #pragma unroll
  for (int c = 0; c < 4; ++c) stage64(Bb, K, n0 + c * 64, BK, &Bs[1][c * 64 * BK]);
  asm volatile("s_waitcnt vmcnt(8)" ::: "memory");   // tile 0 landed
  BAR();

  for (int t = 0; t < NT; ++t) {
    const int cur = t & 1;
    const unsigned short* AL = As[cur];
    const unsigned short* BL = Bs[cur];
    const int  nxtK = (t + 2) * BK;
    const bool more = (t + 2 < NT);

    f16x8 af[4][2], bf[4][2];

    // ---- phase 0: quadrant (mq=0, nq=0) — 12 ds_reads, 16 MFMA
    #pragma unroll
    for (int i = 0; i < 4; ++i) {
      const int row = wm * 128 + i * 16 + fr;
      af[i][0] = *(const f16x8*)&AL[row * BK + fb0];
      af[i][1] = *(const f16x8*)&AL[row * BK + fb1];
    }
    #pragma unroll
    for (int j = 0; j < 2; ++j) {
      const int row = wn * 64 + j * 16 + fr;
      bf[j][0] = *(const f16x8*)&BL[row * BK + fb0];
      bf[j][1] = *(const f16x8*)&BL[row * BK + fb1];
    }
    BAR();
    __builtin_amdgcn_s_setprio(1);
    #pragma unroll
    for (int i = 0; i < 4; ++i)
      #pragma unroll
      for (int j = 0; j < 2; ++j) {
        acc[i][j] = __builtin_amdgcn_mfma_f32_16x16x32_f16(af[i][0], bf[j][0], acc[i][j], 0, 0, 0);
        acc[i][j] = __builtin_amdgcn_mfma_f32_16x16x32_f16(af[i][1], bf[j][1], acc[i][j], 0, 0, 0);
      }
    __builtin_amdgcn_s_setprio(0);
    BAR();

    // ---- phase 1: (mq=0, nq=1) — 4 ds_reads; stage A chunks 0,2 of t+2
    #pragma unroll
    for (int j = 2; j < 4; ++j) {
      const int row = wn * 64 + j * 16 + fr;
      bf[j][0] = *(const f16x8*)&BL[row * BK + fb0];
      bf[j][1] = *(const f16x8*)&BL[row * BK + fb1];
    }
    if (more) {
      stage64(Ab, K, m0 +   0, nxtK, &As[cur][0]);
      stage64(Ab, K, m0 + 128, nxtK, &As[cur][128 * BK]);
    }
    BAR();
    __builtin_amdgcn_s_setprio(1);
    #pragma unroll
    for (int i = 0; i < 4; ++i)
      #pragma unroll
      for (int j = 2; j < 4; ++j) {
        acc[i][j] = __builtin_amdgcn_mfma_f32_16x16x32_f16(af[i][0], bf[j][0], acc[i][j], 0, 0, 0);
        acc[i][j] = __builtin_amdgcn_mfma_f32_16x16x32_f16(af[i][1], bf[j][1], acc[i][j], 0, 0, 0);
      }
    __builtin_amdgcn_s_setprio(0);
    BAR();

    // ---- phase 2: (mq=1, nq=0) — 8 ds_reads; stage B chunks 0,1 of t+2
    #pragma unroll
    for (int i = 0; i < 4; ++i) {
      const int row = wm * 128 + 64 + i * 16 + fr;
      af[i][0] = *(const f16x8*)&AL[row * BK + fb0];
      af[i][1] = *(const f16x8*)&AL[row * BK + fb1];
    }
    if (more) {
      stage64(Bb, K, n0 +   0, nxtK, &Bs[cur][0]);
      stage64(Bb, K, n0 +  64, nxtK, &Bs[cur][64 * BK]);
    }
    BAR();
    __builtin_amdgcn_s_setprio(1);
    #pragma unroll
    for (int i = 0; i < 4; ++i)
      #pragma unroll
      for (int j = 0; j < 2; ++j) {
        acc[4 + i][j] = __builtin_amdgcn_mfma_f32_16x16x32_f16(af[i][0], bf[j][0], acc[4 + i][j], 0, 0, 0);
        acc[4 + i][j] = __builtin_amdgcn_mfma_f32_16x16x32_f16(af[i][1], bf[j][1], acc[4 + i][j], 0, 0, 0);
      }
    __builtin_amdgcn_s_setprio(0);
    BAR();

    // ---- phase 3: (mq=1, nq=1) — 0 ds_reads; stage A chunks 1,3 + B chunks 2,3
    if (more) {
      stage64(Ab, K, m0 +  64, nxtK, &As[cur][64 * BK]);
      stage64(Ab, K, m0 + 192, nxtK, &As[cur][192 * BK]);
      stage64(Bb, K, n0 + 128, nxtK, &Bs[cur][128 * BK]);
      stage64(Bb, K, n0 + 192, nxtK, &Bs[cur][192 * BK]);
    }
    BAR();
    __builtin_amdgcn_s_setprio(1);
    #pragma unroll
    for (int i = 0; i < 4; ++i)
      #pragma unroll
      for (int j = 2; j < 4; ++j) {
        acc[4 + i][j] = __builtin_amdgcn_mfma_f32_16x16x32_f16(af[i][0], bf[j][0], acc[4 + i][j], 0, 0, 0);
        acc[4 + i][j] = __builtin_amdgcn_mfma_f32_16x16x32_f16(af[i][1], bf[j][1], acc[4 + i][j], 0, 0, 0);
      }
    __builtin_amdgcn_s_setprio(0);
    if (more) asm volatile("s_waitcnt vmcnt(8)" ::: "memory");
    else      asm volatile("s_waitcnt vmcnt(0)" ::: "memory");
    BAR();
  }

  // ---- epilogue ----
  const int col = lane & 15;
  const int rb4 = (lane >> 4) * 4;

  if (MODE == 1) {
    #pragma unroll
    for (int j = 0; j < 4; ++j) {
      const int n  = n0 + wn * 64 + j * 16 + col;
      const float bv = bias[n];
      #pragma unroll
      for (int i = 0; i < 8; ++i) {
        const int mb = m0 + wm * 128 + i * 16 + rb4;
        #pragma unroll
        for (int r = 0; r < 4; ++r)
          ((float*)out0)[(size_t)(mb + r) * N + n] = acc[i][j][r] + bv;
      }
    }
  } else {
    // f16 split outputs via per-wave LDS transpose -> 16B full-line stores.
    constexpr int RS = 72;
    unsigned short* eb = (w < 4) ? ((unsigned short*)As + w * (64 * RS))
                                 : ((unsigned short*)Bs + (w - 4) * (64 * RS));
    const bool zhalf = (n0 >= IN_);   // block-uniform
    float bv[4];
    #pragma unroll
    for (int j = 0; j < 4; ++j) bv[j] = bias[n0 + wn * 64 + j * 16 + col];

    const int lrow = lane >> 3;
    const int lc8  = (lane & 7) * 8;
    unsigned short* dst = zhalf ? out1 : (unsigned short*)out0;
    const int ncol0 = (zhalf ? n0 - IN_ : n0) + wn * 64 + lc8;

    #pragma unroll
    for (int h = 0; h < 2; ++h) {
      asm volatile("s_waitcnt lgkmcnt(0)" ::: "memory");
      #pragma unroll
      for (int i2 = 0; i2 < 4; ++i2)
        #pragma unroll
        for (int j = 0; j < 4; ++j)
          #pragma unroll
          for (int r = 0; r < 4; ++r) {
            const float v = acc[h * 4 + i2][j][r] + bv[j];
            ((_Float16*)eb)[(i2 * 16 + rb4 + r) * RS + j * 16 + col] = (_Float16)v;
          }
      asm volatile("s_waitcnt lgkmcnt(0)" ::: "memory");
      #pragma unroll
      for (int it = 0; it < 8; ++it) {
        const int row = it * 8 + lrow;
        uint4 d = *(const uint4*)&eb[row * RS + lc8];
        if (zhalf) {
          float f[8];
          unpack_h8(d, f);
          d.x = packh2(siluf(f[0]), siluf(f[1]));
          d.y = packh2(siluf(f[2]), siluf(f[3]));
          d.z = packh2(siluf(f[4]), siluf(f[5]));
          d.w = packh2(siluf(f[6]), siluf(f[7]));
        }
        const int m = m0 + wm * 128 + h * 64 + row;
        *(uint4*)(dst + (size_t)m * IN_ + ncol0) = d;
      }
    }
  }
}

// ---------------------------------------------------------------------------
// causal depthwise conv (K=4, left pad 3) + SiLU.  f16 in/out.
// 8 channels x 4 timesteps per thread: 7 row-loads for 4 outputs.
// ---------------------------------------------------------------------------
__launch_bounds__(256)
__global__ void conv_silu_k(const uint4* __restrict__ xm,
                            const float* __restrict__ cw,   // (IN_,1,4)
                            const float* __restrict__ cb,
                            uint4* __restrict__ act)
{
  const int t = blockIdx.x * 256 + threadIdx.x;   // grid sized exactly
  const int c8 = t & 255;                         // channel group (IN_/8)
  const int s4 = (t >> 8) & (S_ / 4 - 1);         // timestep group
  const int b  = t >> 18;
  const int c  = c8 * 8;
  constexpr int RW = IN_ / 8;                     // row stride in uint4

  float w[8][4];
  #pragma unroll
  for (int j = 0; j < 8; ++j)
    *(float4*)w[j] = *(const float4*)(cw + (size_t)(c + j) * 4);
  float bias8[8];
  *(float4*)(bias8)     = *(const float4*)(cb + c);
  *(float4*)(bias8 + 4) = *(const float4*)(cb + c + 4);

  const size_t rowb = ((size_t)b * S_ + s4 * 4) * RW + c8;
  float xf[7][8];
  #pragma unroll
  for (int i = 0; i < 7; ++i) {
    if (s4 == 0 && i < 3) {
      #pragma unroll
      for (int j = 0; j < 8; ++j) xf[i][j] = 0.0f;
    } else {
      unpack_h8(xm[rowb + (long)(i - 3) * RW], xf[i]);
    }
  }

  #pragma unroll
  for (int o = 0; o < 4; ++o) {
    float r[8];
    #pragma unroll
    for (int j = 0; j < 8; ++j) r[j] = bias8[j];
    #pragma unroll
    for (int k = 0; k < 4; ++k)
      #pragma unroll
      for (int j = 0; j < 8; ++j)
        r[j] = fmaf(xf[o + k][j], w[j][k], r[j]);
    uint4 ov;
    ov.x = packh2(siluf(r[0]), siluf(r[1]));
    ov.y = packh2(siluf(r[2]), siluf(r[3]));
    ov.z = packh2(siluf(r[4]), siluf(r[5]));
    ov.w = packh2(siluf(r[6]), siluf(r[7]));
    act[rowb + (size_t)o * RW] = ov;
  }
}

// ---------------------------------------------------------------------------
// grouped 16x16 gate projections + per-chunk scan partials — LINEAR domain
// (r14 configuration — best measured).  f = (1+E_i)/(2+E_f+E_i), i = 1-f;
// g~ = hd+0.5 (hd>=0) or sigmoid(hd).  Backward suffix accumulation in
// 4 blocks of 8: T += i*g~*R; R *= f; close: Ss += exp2(q)*T; q += log2(R).
// ---------------------------------------------------------------------------
__launch_bounds__(256)
__global__ void gates_scan(const unsigned* __restrict__ actb,
                           const float* __restrict__ wf,
                           const float* __restrict__ wi,
                           const float* __restrict__ wh,
                           float2* __restrict__ part)   // [B_*IN_][NCH_]
{
  const int T  = blockIdx.x * 256 + threadIdx.x;
  const int o  = T & 15;
  const int g  = (T >> 4) & 127;
  const int ck = (T >> 11) & (NCH_ - 1);
  const int b  = T >> 18;

  h2 Wf2[8], Wi2[8], Wh2[8];
  const float* pf = wf + ((size_t)g * 16 + o) * 16;
  const float* pi = wi + ((size_t)g * 16 + o) * 16;
  const float* ph = wh + ((size_t)g * 16 + o) * 16;
  #pragma unroll
  for (int i = 0; i < 8; ++i) {
    Wf2[i] = pkrtz(pf[2 * i] * LOG2E_, pf[2 * i + 1] * LOG2E_);   // base-2 gates
    Wi2[i] = pkrtz(pi[2 * i] * LOG2E_, pi[2 * i + 1] * LOG2E_);
    Wh2[i] = pkrtz(ph[2 * i], ph[2 * i + 1]);
  }

  float q = 0.0f, Ss = 0.0f;
  // start at the LAST step of the chunk, walk backward in time
  const unsigned* ap = actb + ((size_t)b * S_ + (size_t)ck * CS_ + (CS_ - 1)) * (IN_ / 2) + g * 8;
  for (int blk = 0; blk < 4; ++blk) {
    float R = 1.0f, Tacc = 0.0f;
    #pragma unroll
    for (int s = 0; s < 8; ++s) {
      union { uint4 u; h2 h[4]; } A0, A1;
      A0.u = *(const uint4*)(ap);
      A1.u = *(const uint4*)(ap + 4);
      ap -= IN_ / 2;
      float fg = 0.0f, ig = 0.0f, hd = 0.0f;   // fg, ig in base-2 units
      #pragma unroll
      for (int i = 0; i < 4; ++i) {
        fg = __builtin_amdgcn_fdot2(A0.h[i], Wf2[i], fg, false);
        ig = __builtin_amdgcn_fdot2(A0.h[i], Wi2[i], ig, false);
        hd = __builtin_amdgcn_fdot2(A0.h[i], Wh2[i], hd, false);
      }
      #pragma unroll
      for (int i = 0; i < 4; ++i) {
        fg = __builtin_amdgcn_fdot2(A1.h[i], Wf2[i + 4], fg, false);
        ig = __builtin_amdgcn_fdot2(A1.h[i], Wi2[i + 4], ig, false);
        hd = __builtin_amdgcn_fdot2(A1.h[i], Wh2[i + 4], hd, false);
      }
      const float Ef = __builtin_amdgcn_exp2f(-fg);            // e^-FG
      const float Ei = __builtin_amdgcn_exp2f(-ig);            // e^-IG
      const float rden = __builtin_amdgcn_rcpf(2.0f + Ef + Ei);
      const float f = (1.0f + Ei) * rden;
      const float i = (1.0f + Ef) * rden;
      const float Eh = __builtin_amdgcn_exp2f(-hd * LOG2E_);   // e^-hd
      const float gneg = __builtin_amdgcn_rcpf(1.0f + Eh);     // sigmoid(hd)
      const float gt = (hd >= 0.0f) ? (hd + 0.5f + EPS_) : gneg;
      Tacc = fmaf(i * gt, R, Tacc);
      R *= f;
    }
    Ss = fmaf(__builtin_amdgcn_exp2f(q), Tacc, Ss);
    q += __builtin_amdgcn_logf(R);   // v_log_f32 = log2
  }
  // p = q (log2 of full product);  L = -p + log2(Ss)
  part[((size_t)(b * IN_ + g * 16 + o)) * NCH_ + ck] =
      make_float2(q, -q + __builtin_amdgcn_logf(Ss + 1e-44f));
}

// ---------------------------------------------------------------------------
// combine chunk partials -> h_last[b, c]   (base-2 domain throughout)
// ---------------------------------------------------------------------------
__launch_bounds__(256)
__global__ void combine_k(const float2* __restrict__ part, float* __restrict__ hlast)
{
  const int seq = blockIdx.x * 256 + threadIdx.x;
  if (seq >= B_ * IN_) return;
  const float2* pp = part + (size_t)seq * NCH_;
  float P = 0.0f, Mx = -INFINITY, Ss = 0.0f;
  for (int c = 0; c < NCH_; ++c) {
    const float2 al = pp[c];
    const float v = al.y - P;
    const float m = fmaxf(Mx, v);
    Ss = Ss * __builtin_amdgcn_exp2f(Mx - m) + __builtin_amdgcn_exp2f(v - m);
    Mx = m;
    P += al.x;
  }
  hlast[seq] = __builtin_amdgcn_exp2f(P + Mx) * Ss;
}

// ---------------------------------------------------------------------------
// G = (h_last + skip*act) * silu(z), written in place over the z buffer.
// ---------------------------------------------------------------------------
__launch_bounds__(256)
__global__ void gfuse_k(const unsigned* __restrict__ actb,
                        unsigned* __restrict__ zb,
                        const float* __restrict__ hlast,
                        const float* __restrict__ skipv)
{
  const size_t total  = (size_t)B_ * S_ * IN_ / 8;
  const size_t stride = (size_t)gridDim.x * blockDim.x;
  for (size_t t = (size_t)blockIdx.x * blockDim.x + threadIdx.x; t < total; t += stride) {
    const size_t e = t * 8;
    const int    c = (int)(e % IN_);
    const int    b = (int)(e / ((size_t)S_ * IN_));
    float a[8], z[8], hl[8], sk[8];
    unpack_h8(*(const uint4*)(actb + e / 2), a);
    unpack_h8(*(const uint4*)(zb   + e / 2), z);
    *(float4*)(hl)     = *(const float4*)(hlast + (size_t)b * IN_ + c);
    *(float4*)(hl + 4) = *(const float4*)(hlast + (size_t)b * IN_ + c + 4);
    *(float4*)(sk)     = *(const float4*)(skipv + c);
    *(float4*)(sk + 4) = *(const float4*)(skipv + c + 4);
    float g[8];
    #pragma unroll
    for (int j = 0; j < 8; ++j) g[j] = (hl[j] + sk[j] * a[j]) * z[j];
    uint4 o;
    o.x = packh2(g[0], g[1]);
    o.y = packh2(g[2], g[3]);
    o.z = packh2(g[4], g[5]);
    o.w = packh2(g[6], g[7]);
    *(uint4*)(zb + e / 2) = o;
  }
}

// ---------------------------------------------------------------------------
extern "C" void kernel_launch(void* const* d_in, const int* in_sizes, int n_in,
                              void* d_out, int out_size, void* d_ws, size_t ws_size,
                              hipStream_t stream)
{
  const float* x     = (const float*)d_in[0];
  const float* w_up  = (const float*)d_in[1];
  const float* b_up  = (const float*)d_in[2];
  const float* cw    = (const float*)d_in[3];
  const float* cb    = (const float*)d_in[4];
  const float* skipv = (const float*)d_in[5];
  const float* w_f   = (const float*)d_in[6];
  const float* w_i   = (const float*)d_in[7];
  const float* w_h   = (const float*)d_in[8];
  const float* w_dn  = (const float*)d_in[9];
  const float* b_dn  = (const float*)d_in[10];
  float* out = (float*)d_out;

  // workspace layout with lifetime-based aliasing (max ~210 MB)
  char* ws = (char*)d_ws;
  unsigned short* xminb = (unsigned short*)(ws);
  unsigned short* wdb   = (unsigned short*)(ws);                    // after conv
  float2*         part  = (float2*)(ws + 8388608ULL);               // after conv
  float*          hlast = (float*)(ws + 16777216ULL);               // after conv
  unsigned short* zb    = (unsigned short*)(ws + 67108864ULL);
  unsigned short* actb  = (unsigned short*)(ws + 134217728ULL);
  unsigned short* xb    = (unsigned short*)(ws + 134217728ULL);     // pre-conv alias
  unsigned short* wub   = (unsigned short*)(ws + 201326592ULL);

  const int M = B_ * S_;   // 16384

  // 0) fp32 -> f16 conversions for MFMA operands (single launch)
  cvt_f16_2<<<2560, 256, 0, stream>>>(
      x,    (unsigned*)xb,  (long)M * D_ / 8,
      w_up, (unsigned*)wub, (long)2 * IN_ * D_ / 8);

  // 1) proj-up: xb @ wub^T + b_up -> xmin(f16) | silu(z)(f16)
  gemm_mfma<0><<<dim3((2 * IN_) / 256, M / 256), 512, 0, stream>>>(
      xb, wub, b_up, xminb, (unsigned short*)zb, M, 2 * IN_, D_);

  // 2) causal depthwise conv + SiLU -> act(f16)  (4 steps x 8 ch / thread)
  conv_silu_k<<<(B_ * (S_ / 4) * (IN_ / 8)) / 256, 256, 0, stream>>>(
      (const uint4*)xminb, cw, cb, (uint4*)actb);

  // 2b) w_down -> f16 (into region freed by xminb)
  cvt_f16<<<256, 256, 0, stream>>>(w_dn, (unsigned*)wdb, (long)D_ * IN_ / 8);

  // 3) grouped gate projections + chunked scan partials (linear domain)
  gates_scan<<<(B_ * 128 * 16 * NCH_) / 256, 256, 0, stream>>>(
      (const unsigned*)actb, w_f, w_i, w_h, part);

  // 4) combine partials -> h_last
  combine_k<<<(B_ * IN_ + 255) / 256, 256, 0, stream>>>(part, hlast);

  // 5) G = (h_last + skip*act) * silu(z), in place over zb
  gfuse_k<<<2048, 256, 0, stream>>>((const unsigned*)actb, (unsigned*)zb, hlast, skipv);

  // 6) proj-down: G(f16) @ wdb^T + b_dn -> out (fp32)
  gemm_mfma<1><<<dim3(D_ / 256, M / 256), 512, 0, stream>>>(
      zb, wdb, b_dn, out, nullptr, M, D_, IN_);
}